// Round 15
// baseline (117.225 us; speedup 1.0000x reference)
//
#include <hip/hip_runtime.h>

#define N 8192
#define D 256

typedef short short8 __attribute__((ext_vector_type(8)));
typedef float f32x4 __attribute__((ext_vector_type(4)));

__device__ __forceinline__ unsigned short f2bf(float f) {
    unsigned int u = __float_as_uint(f);
    u += 0x7fffu + ((u >> 16) & 1u);   // RNE
    return (unsigned short)(u >> 16);
}
__device__ __forceinline__ float bf2f(unsigned short h) {
    return __uint_as_float(((unsigned int)h) << 16);
}

// async global->LDS, 16B per lane; dst is wave-uniform base + lane*16
#define GLDS16(g, l) __builtin_amdgcn_global_load_lds(                      \
    (const __attribute__((address_space(1))) void*)(g),                     \
    (__attribute__((address_space(3))) void*)(l), 16, 0, 0)

// Kernel 0: fp32 -> bf16 conversion into FRAGMENT-MAJOR layout xb2 (R13):
// 16B chunk ((row>>4)*8 + kk)*64 + lane holds
// X[(row>>4)*16 + (lane&15)][kk*32 + (lane>>4)*8 .. +8) as bf16.
// One WAVE per 16-row group, grid 512 x 64 threads -> 2 waves/CU on all 256
// CUs (the old 128-block version left half the chip idle). Also row squared
// norms + zero S/L accumulators.
__global__ __launch_bounds__(64) void k_cvt(const float* __restrict__ x,
                                            unsigned short* __restrict__ xb2,
                                            float* __restrict__ sq,
                                            float* __restrict__ Sarr,
                                            float* __restrict__ Larr) {
    const int lane = threadIdx.x & 63;
    const int c = lane & 15, q8 = lane >> 4;
    const int grp = blockIdx.x;               // 16-row group
    const int row = grp * 16 + c;

    float ssum = 0.0f;
#pragma unroll
    for (int kk = 0; kk < 8; ++kk) {
        const float4* gp = (const float4*)(x + (size_t)row * D + kk * 32 + q8 * 8);
        float4 v0 = gp[0], v1 = gp[1];
        unsigned short h[8];
        h[0] = f2bf(v0.x); h[1] = f2bf(v0.y); h[2] = f2bf(v0.z); h[3] = f2bf(v0.w);
        h[4] = f2bf(v1.x); h[5] = f2bf(v1.y); h[6] = f2bf(v1.z); h[7] = f2bf(v1.w);
        short8 p;
#pragma unroll
        for (int i = 0; i < 8; ++i) {
            float f = bf2f(h[i]);
            ssum = fmaf(f, f, ssum);
            p[i] = (short)h[i];
        }
        ((short8*)xb2)[(grp * 8 + kk) * 64 + lane] = p;
    }
    ssum += __shfl_xor(ssum, 16, 64);
    ssum += __shfl_xor(ssum, 32, 64);
    if (q8 == 0) {
        sq[row] = ssum;
        Sarr[row] = 0.0f;
        Larr[row] = 0.0f;
    }
}

// Kernel 1: R13 pipeline at TRUE 4 blocks/CU. 64 rows/wave (256-row blocks,
// av = 128 VGPRs), fragment-major xb2 (coalesced A loads + contiguous GLDS16
// staging), fragment-sequential zero-conflict LDS, screened exp2 epilogue —
// all unchanged from R13. Occupancy fix: grid (32,32) = 1024 blocks (grid was
// the hidden 2-blocks/CU cap in R8/R10/R13: 512 blocks = exactly 2/CU) with
// 2 x 16 KB ping-pong (32-col subtiles, 8 per block). __launch_bounds__(256,2)
// keeps the allocator at natural ~112 VGPR (R11's (256,4) forced 64 -> spill);
// HW residency = min(LDS 160/32=5, VGPR 512/112=4 waves/SIMD, grid 4/CU) = 4.
__global__ __launch_bounds__(256, 2) void k_gram(const unsigned short* __restrict__ xb2,
                                                 const float* __restrict__ sq,
                                                 const float* __restrict__ temp,
                                                 float* __restrict__ Sarr,
                                                 float* __restrict__ Larr) {
    __shared__ unsigned short Bs[2][32 * D];   // 2 x 16 KB, fragment-sequential

    const int tid = threadIdx.x;
    const int wv = tid >> 6, lane = tid & 63;
    const int q8 = lane >> 4, c = lane & 15;
    const int rowbase = blockIdx.x * 256;
    const int ybase = blockIdx.y * 256;
    const float T = temp[0];
    const float LOG2E = 1.44269504f;
    const float s2 = -LOG2E / (2.0f * T * T);   // log2-scaled; t2 = c2*g + ar + bc
    const float c2 = -2.0f * s2;

    // A fragments: wave wv owns rows rowbase + wv*64 .. +63 (coalesced)
    short8 av[4][8];
#pragma unroll
    for (int tr = 0; tr < 4; ++tr) {
        const int grp = (rowbase >> 4) + wv * 4 + tr;
#pragma unroll
        for (int kk = 0; kk < 8; ++kk)
            av[tr][kk] = ((const short8*)xb2)[(grp * 8 + kk) * 64 + lane];
    }
    float ar[16];   // sq[row] * s2 (negative)
#pragma unroll
    for (int tr = 0; tr < 4; ++tr)
#pragma unroll
        for (int r = 0; r < 4; ++r)
            ar[tr * 4 + r] = sq[rowbase + wv * 64 + tr * 16 + q8 * 4 + r] * s2;
    float armax = ar[0];
#pragma unroll
    for (int k = 1; k < 16; ++k) armax = fmaxf(armax, ar[k]);

    float Sr[16], Mr[16];
#pragma unroll
    for (int k = 0; k < 16; ++k) { Sr[k] = 0.f; Mr[k] = 0.f; }

    // staging: 32-col subtile = contiguous 16 KB of xb2 = 16 segs of 1 KB;
    // wave wv stages segs wv*4 .. +3; src = chunkbase + s*512 + lane*8
#pragma unroll
    for (int g2 = 0; g2 < 4; ++g2) {
        int s = wv * 4 + g2;
        const unsigned short* src =
            xb2 + (size_t)(ybase >> 4) * 4096 + s * 512 + lane * 8;
        GLDS16(src, &Bs[0][0] + s * 512);
    }

    for (int ht = 0; ht < 8; ++ht) {
        const int tilebase = ybase + ht * 32;
        const int cur = ht & 1;

        __syncthreads();   // drains stage of ht; fences buffer reuse (ht-2)

        if (ht < 7) {
            const size_t nchunk = (size_t)((tilebase + 32) >> 4) * 4096;
#pragma unroll
            for (int g2 = 0; g2 < 4; ++g2) {
                int s = wv * 4 + g2;
                const unsigned short* src = xb2 + nchunk + s * 512 + lane * 8;
                GLDS16(src, &Bs[cur ^ 1][0] + s * 512);
            }
        }

#pragma unroll
        for (int tc = 0; tc < 2; ++tc) {
            const float bc = sq[tilebase + tc * 16 + c] * s2;
            // fragment-sequential: lane's data for (tc,kk) at (tc*8+kk)*1024B + lane*16B
            const unsigned short* bb = &Bs[cur][0] + tc * 8 * 512 + lane * 8;

            short8 bva[4];
#pragma unroll
            for (int kk = 0; kk < 4; ++kk)
                bva[kk] = *(const short8*)(bb + kk * 512);

            f32x4 acc[4];
#pragma unroll
            for (int tr = 0; tr < 4; ++tr)
#pragma unroll
                for (int r = 0; r < 4; ++r) acc[tr][r] = 0.0f;

#pragma unroll
            for (int kk = 0; kk < 4; ++kk)
#pragma unroll
                for (int tr = 0; tr < 4; ++tr)
                    acc[tr] = __builtin_amdgcn_mfma_f32_16x16x32_bf16(
                        av[tr][kk], bva[kk], acc[tr], 0, 0, 0);

            short8 bvb[4];
#pragma unroll
            for (int kk = 0; kk < 4; ++kk)
                bvb[kk] = *(const short8*)(bb + (kk + 4) * 512);

#pragma unroll
            for (int kk = 0; kk < 4; ++kk)
#pragma unroll
                for (int tr = 0; tr < 4; ++tr)
                    acc[tr] = __builtin_amdgcn_mfma_f32_16x16x32_bf16(
                        av[tr][kk + 4], bvb[kk], acc[tr], 0, 0, 0);

            // screen: conservative upper bound on t2 over this lane's 16 elems
            float gmax = acc[0][0];
#pragma unroll
            for (int tr = 0; tr < 4; ++tr)
#pragma unroll
                for (int r = 0; r < 4; ++r) gmax = fmaxf(gmax, acc[tr][r]);
            const float bound = fmaf(gmax, c2, armax + bc);

            if (__any(bound >= -115.0f)) {
                // exact slow path (diagonal-touching subtiles, ~1%)
#pragma unroll
                for (int tr = 0; tr < 4; ++tr)
#pragma unroll
                    for (int r = 0; r < 4; ++r) {
                        float g = acc[tr][r];
                        float t2 = fminf(fmaf(g, c2, ar[tr * 4 + r] + bc), 0.0f);
                        float e = __builtin_amdgcn_exp2f(t2);
                        Sr[tr * 4 + r] += e;
                        Mr[tr * 4 + r] = fmaf(e, t2, Mr[tr * 4 + r]);
                    }
            }
            // else: all values underflow fp32 -> contribute exactly 0
        }
    }

    // row-sum commit: reduce across the 16 col-lanes (lane bits 0..3)
#pragma unroll
    for (int m = 1; m <= 8; m <<= 1)
#pragma unroll
        for (int k = 0; k < 16; ++k) {
            Sr[k] += __shfl_xor(Sr[k], m, 64);
            Mr[k] += __shfl_xor(Mr[k], m, 64);
        }
    if (c == 0) {
        const float LN2 = 0.69314718f;   // Mr holds sum e*log2(k); rescale to ln
#pragma unroll
        for (int k = 0; k < 16; ++k) {
            int row = rowbase + wv * 64 + (k >> 2) * 16 + q8 * 4 + (k & 3);
            atomicAdd(&Sarr[row], Sr[k]);
            atomicAdd(&Larr[row], Mr[k] * LN2);
        }
    }
}

// Kernel 2 (merged ctrl+scale): per row H = log(S) - L/S,
// cs = sigmoid(-(H - target)/T); write scaled features + control signal.
__global__ __launch_bounds__(256) void k_finish(const float* __restrict__ x,
                                                const float* __restrict__ Sarr,
                                                const float* __restrict__ Larr,
                                                const float* __restrict__ target,
                                                const float* __restrict__ temp,
                                                float* __restrict__ out) {
    const int gid = blockIdx.x * 256 + threadIdx.x;  // float4 index
    const int row = gid >> 6;                        // 64 float4 per row
    float S = Sarr[row], L = Larr[row];
    float H = __logf(S) - L / S;
    float z = (H - target[0]) / temp[0];
    float cs = 1.0f / (1.0f + __expf(z));
    float4 v = ((const float4*)x)[gid];
    float4 o;
    o.x = v.x * cs; o.y = v.y * cs; o.z = v.z * cs; o.w = v.w * cs;
    ((float4*)out)[gid] = o;
    if ((gid & 63) == 0) out[(size_t)N * D + row] = cs;  // control_signal section
}

extern "C" void kernel_launch(void* const* d_in, const int* in_sizes, int n_in,
                              void* d_out, int out_size, void* d_ws, size_t ws_size,
                              hipStream_t stream) {
    const float* x = (const float*)d_in[0];       // features [4,2048,256]
    const float* target = (const float*)d_in[7];  // target_entropy [1]
    const float* temp = (const float*)d_in[8];    // temperature [1]
    float* out = (float*)d_out;

    float* wsf = (float*)d_ws;
    float* sq = wsf;
    float* Sarr = wsf + N;
    float* Larr = wsf + 2 * N;

    // fragment-major bf16 copy of X: in ws if it fits, else park in d_out's
    // first 4 MB (k_finish only writes d_out after k_gram has consumed xb2)
    const size_t need = 3 * (size_t)N * sizeof(float) + (size_t)N * D * sizeof(unsigned short);
    unsigned short* xb2 = (ws_size >= need) ? (unsigned short*)(wsf + 3 * N)
                                            : (unsigned short*)d_out;

    k_cvt<<<N / 16, 64, 0, stream>>>(x, xb2, sq, Sarr, Larr);
    k_gram<<<dim3(32, 32), 256, 0, stream>>>(xb2, sq, temp, Sarr, Larr);
    k_finish<<<(N * (D / 4)) / 256, 256, 0, stream>>>(x, Sarr, Larr, target, temp, out);
}

// Round 16
// 111.290 us; speedup vs baseline: 1.0533x; 1.0533x over previous
//
#include <hip/hip_runtime.h>

#define N 8192
#define D 256

typedef short short8 __attribute__((ext_vector_type(8)));
typedef float f32x4 __attribute__((ext_vector_type(4)));

__device__ __forceinline__ unsigned short f2bf(float f) {
    unsigned int u = __float_as_uint(f);
    u += 0x7fffu + ((u >> 16) & 1u);   // RNE
    return (unsigned short)(u >> 16);
}
__device__ __forceinline__ float bf2f(unsigned short h) {
    return __uint_as_float(((unsigned int)h) << 16);
}

// async global->LDS, 16B per lane; dst is wave-uniform base + lane*16
#define GLDS16(g, l) __builtin_amdgcn_global_load_lds(                      \
    (const __attribute__((address_space(1))) void*)(g),                     \
    (__attribute__((address_space(3))) void*)(l), 16, 0, 0)

// Kernel 0 (R15 version): fp32 -> bf16 into FRAGMENT-MAJOR layout xb2:
// 16B chunk ((row>>4)*8 + kk)*64 + lane holds
// X[(row>>4)*16 + (lane&15)][kk*32 + (lane>>4)*8 .. +8) as bf16.
// One wave per 16-row group, grid 512 x 64 -> all 256 CUs active.
// Also row squared norms + zero S/L accumulators.
__global__ __launch_bounds__(64) void k_cvt(const float* __restrict__ x,
                                            unsigned short* __restrict__ xb2,
                                            float* __restrict__ sq,
                                            float* __restrict__ Sarr,
                                            float* __restrict__ Larr) {
    const int lane = threadIdx.x & 63;
    const int c = lane & 15, q8 = lane >> 4;
    const int grp = blockIdx.x;               // 16-row group
    const int row = grp * 16 + c;

    float ssum = 0.0f;
#pragma unroll
    for (int kk = 0; kk < 8; ++kk) {
        const float4* gp = (const float4*)(x + (size_t)row * D + kk * 32 + q8 * 8);
        float4 v0 = gp[0], v1 = gp[1];
        unsigned short h[8];
        h[0] = f2bf(v0.x); h[1] = f2bf(v0.y); h[2] = f2bf(v0.z); h[3] = f2bf(v0.w);
        h[4] = f2bf(v1.x); h[5] = f2bf(v1.y); h[6] = f2bf(v1.z); h[7] = f2bf(v1.w);
        short8 p;
#pragma unroll
        for (int i = 0; i < 8; ++i) {
            float f = bf2f(h[i]);
            ssum = fmaf(f, f, ssum);
            p[i] = (short)h[i];
        }
        ((short8*)xb2)[(grp * 8 + kk) * 64 + lane] = p;
    }
    ssum += __shfl_xor(ssum, 16, 64);
    ssum += __shfl_xor(ssum, 32, 64);
    if (q8 == 0) {
        sq[row] = ssum;
        Sarr[row] = 0.0f;
        Larr[row] = 0.0f;
    }
}

// Kernel 1 (R13 version — best measured: 40 us): 64 rows/wave (256-row
// blocks, av = 128 VGPRs, fragment-major coalesced loads), grid (32,16) =
// 512 blocks, 8 x 64-col subtiles through 2 x 32 KB ping-pong
// fragment-sequential LDS (0 bank conflicts, contiguous GLDS16 staging),
// screened exp2 epilogue (tiles whose conservative bound proves fp32
// underflow contribute exactly 0, matching the reference's own arithmetic).
// Floor evidence (R6-R15): this structure is latency-pinned at ~40 us;
// work halving (R14), occupancy (R12/R15), conflicts (R10), barriers (R9),
// and staging pipelining (R6) all failed to move it.
__global__ __launch_bounds__(256, 2) void k_gram(const unsigned short* __restrict__ xb2,
                                                 const float* __restrict__ sq,
                                                 const float* __restrict__ temp,
                                                 float* __restrict__ Sarr,
                                                 float* __restrict__ Larr) {
    __shared__ unsigned short Bs[2][64 * D];   // 2 x 32 KB, fragment-sequential

    const int tid = threadIdx.x;
    const int wv = tid >> 6, lane = tid & 63;
    const int q8 = lane >> 4, c = lane & 15;
    const int rowbase = blockIdx.x * 256;
    const int ybase = blockIdx.y * 512;
    const float T = temp[0];
    const float LOG2E = 1.44269504f;
    const float s2 = -LOG2E / (2.0f * T * T);   // log2-scaled; t2 = c2*g + ar + bc
    const float c2 = -2.0f * s2;

    // A fragments: wave wv owns rows rowbase + wv*64 .. +63 (coalesced)
    short8 av[4][8];
#pragma unroll
    for (int tr = 0; tr < 4; ++tr) {
        const int grp = (rowbase >> 4) + wv * 4 + tr;
#pragma unroll
        for (int kk = 0; kk < 8; ++kk)
            av[tr][kk] = ((const short8*)xb2)[(grp * 8 + kk) * 64 + lane];
    }
    float ar[16];   // sq[row] * s2 (negative)
#pragma unroll
    for (int tr = 0; tr < 4; ++tr)
#pragma unroll
        for (int r = 0; r < 4; ++r)
            ar[tr * 4 + r] = sq[rowbase + wv * 64 + tr * 16 + q8 * 4 + r] * s2;
    float armax = ar[0];
#pragma unroll
    for (int k = 1; k < 16; ++k) armax = fmaxf(armax, ar[k]);

    float Sr[16], Mr[16];
#pragma unroll
    for (int k = 0; k < 16; ++k) { Sr[k] = 0.f; Mr[k] = 0.f; }

    // staging: 64-col subtile = contiguous 32 KB of xb2 = 32 segs of 1 KB;
    // wave wv stages segs wv*8 .. +7; src = chunkbase + s*512 + lane*8
#pragma unroll
    for (int g2 = 0; g2 < 8; ++g2) {
        int s = wv * 8 + g2;
        const unsigned short* src =
            xb2 + (size_t)(ybase >> 4) * 4096 + s * 512 + lane * 8;
        GLDS16(src, &Bs[0][0] + s * 512);
    }

    for (int ht = 0; ht < 8; ++ht) {
        const int tilebase = ybase + ht * 64;
        const int cur = ht & 1;

        __syncthreads();   // drains stage of ht; fences buffer reuse (ht-2)

        if (ht < 7) {
            const size_t nchunk = (size_t)((tilebase + 64) >> 4) * 4096;
#pragma unroll
            for (int g2 = 0; g2 < 8; ++g2) {
                int s = wv * 8 + g2;
                const unsigned short* src = xb2 + nchunk + s * 512 + lane * 8;
                GLDS16(src, &Bs[cur ^ 1][0] + s * 512);
            }
        }

#pragma unroll
        for (int tc = 0; tc < 4; ++tc) {
            const float bc = sq[tilebase + tc * 16 + c] * s2;
            // fragment-sequential: lane's data for (tc,kk) at (tc*8+kk)*1024B + lane*16B
            const unsigned short* bb = &Bs[cur][0] + tc * 8 * 512 + lane * 8;

            short8 bva[4];
#pragma unroll
            for (int kk = 0; kk < 4; ++kk)
                bva[kk] = *(const short8*)(bb + kk * 512);

            f32x4 acc[4];
#pragma unroll
            for (int tr = 0; tr < 4; ++tr)
#pragma unroll
                for (int r = 0; r < 4; ++r) acc[tr][r] = 0.0f;

#pragma unroll
            for (int kk = 0; kk < 4; ++kk)
#pragma unroll
                for (int tr = 0; tr < 4; ++tr)
                    acc[tr] = __builtin_amdgcn_mfma_f32_16x16x32_bf16(
                        av[tr][kk], bva[kk], acc[tr], 0, 0, 0);

            short8 bvb[4];
#pragma unroll
            for (int kk = 0; kk < 4; ++kk)
                bvb[kk] = *(const short8*)(bb + (kk + 4) * 512);

#pragma unroll
            for (int kk = 0; kk < 4; ++kk)
#pragma unroll
                for (int tr = 0; tr < 4; ++tr)
                    acc[tr] = __builtin_amdgcn_mfma_f32_16x16x32_bf16(
                        av[tr][kk + 4], bvb[kk], acc[tr], 0, 0, 0);

            // screen: conservative upper bound on t2 over this lane's 16 elems
            float gmax = acc[0][0];
#pragma unroll
            for (int tr = 0; tr < 4; ++tr)
#pragma unroll
                for (int r = 0; r < 4; ++r) gmax = fmaxf(gmax, acc[tr][r]);
            const float bound = fmaf(gmax, c2, armax + bc);

            if (__any(bound >= -115.0f)) {
                // exact slow path (diagonal-touching subtiles, ~1%)
#pragma unroll
                for (int tr = 0; tr < 4; ++tr)
#pragma unroll
                    for (int r = 0; r < 4; ++r) {
                        float g = acc[tr][r];
                        float t2 = fminf(fmaf(g, c2, ar[tr * 4 + r] + bc), 0.0f);
                        float e = __builtin_amdgcn_exp2f(t2);
                        Sr[tr * 4 + r] += e;
                        Mr[tr * 4 + r] = fmaf(e, t2, Mr[tr * 4 + r]);
                    }
            }
            // else: all values underflow fp32 -> contribute exactly 0
        }
    }

    // row-sum commit: reduce across the 16 col-lanes (lane bits 0..3)
#pragma unroll
    for (int m = 1; m <= 8; m <<= 1)
#pragma unroll
        for (int k = 0; k < 16; ++k) {
            Sr[k] += __shfl_xor(Sr[k], m, 64);
            Mr[k] += __shfl_xor(Mr[k], m, 64);
        }
    if (c == 0) {
        const float LN2 = 0.69314718f;   // Mr holds sum e*log2(k); rescale to ln
#pragma unroll
        for (int k = 0; k < 16; ++k) {
            int row = rowbase + wv * 64 + (k >> 2) * 16 + q8 * 4 + (k & 3);
            atomicAdd(&Sarr[row], Sr[k]);
            atomicAdd(&Larr[row], Mr[k] * LN2);
        }
    }
}

// Kernel 2 (merged ctrl+scale): per row H = log(S) - L/S,
// cs = sigmoid(-(H - target)/T); write scaled features + control signal.
__global__ __launch_bounds__(256) void k_finish(const float* __restrict__ x,
                                                const float* __restrict__ Sarr,
                                                const float* __restrict__ Larr,
                                                const float* __restrict__ target,
                                                const float* __restrict__ temp,
                                                float* __restrict__ out) {
    const int gid = blockIdx.x * 256 + threadIdx.x;  // float4 index
    const int row = gid >> 6;                        // 64 float4 per row
    float S = Sarr[row], L = Larr[row];
    float H = __logf(S) - L / S;
    float z = (H - target[0]) / temp[0];
    float cs = 1.0f / (1.0f + __expf(z));
    float4 v = ((const float4*)x)[gid];
    float4 o;
    o.x = v.x * cs; o.y = v.y * cs; o.z = v.z * cs; o.w = v.w * cs;
    ((float4*)out)[gid] = o;
    if ((gid & 63) == 0) out[(size_t)N * D + row] = cs;  // control_signal section
}

extern "C" void kernel_launch(void* const* d_in, const int* in_sizes, int n_in,
                              void* d_out, int out_size, void* d_ws, size_t ws_size,
                              hipStream_t stream) {
    const float* x = (const float*)d_in[0];       // features [4,2048,256]
    const float* target = (const float*)d_in[7];  // target_entropy [1]
    const float* temp = (const float*)d_in[8];    // temperature [1]
    float* out = (float*)d_out;

    float* wsf = (float*)d_ws;
    float* sq = wsf;
    float* Sarr = wsf + N;
    float* Larr = wsf + 2 * N;

    // fragment-major bf16 copy of X: in ws if it fits, else park in d_out's
    // first 4 MB (k_finish only writes d_out after k_gram has consumed xb2)
    const size_t need = 3 * (size_t)N * sizeof(float) + (size_t)N * D * sizeof(unsigned short);
    unsigned short* xb2 = (ws_size >= need) ? (unsigned short*)(wsf + 3 * N)
                                            : (unsigned short*)d_out;

    k_cvt<<<N / 16, 64, 0, stream>>>(x, xb2, sq, Sarr, Larr);
    k_gram<<<dim3(32, 16), 256, 0, stream>>>(xb2, sq, temp, Sarr, Larr);
    k_finish<<<(N * (D / 4)) / 256, 256, 0, stream>>>(x, Sarr, Larr, target, temp, out);
}